// Round 1
// baseline (350.856 us; speedup 1.0000x reference)
//
#include <hip/hip_runtime.h>
#include <hip/hip_bf16.h>

// ---------------- helpers ----------------
typedef __attribute__((ext_vector_type(8))) short short8;
typedef __attribute__((ext_vector_type(4))) float floatx4;

__device__ __forceinline__ unsigned short f2bfu(float f) {
    unsigned u = __float_as_uint(f);
    unsigned rounding = 0x7fffu + ((u >> 16) & 1u);
    return (unsigned short)((u + rounding) >> 16);
}
__device__ __forceinline__ float bfu2f(unsigned short u) {
    return __uint_as_float(((unsigned)u) << 16);
}

#define B_  8
#define N_  2048
#define C_  512
#define NC_ 16   // clusters

// ---------------- convert kernels ----------------
__global__ __launch_bounds__(256) void cvt_x(const float4* __restrict__ x,
                                             unsigned short* __restrict__ xbf) {
    size_t i = (size_t)blockIdx.x * 256 + threadIdx.x;   // 4 floats per thread
    float4 f = x[i];
    unsigned short u0 = f2bfu(f.x), u1 = f2bfu(f.y), u2 = f2bfu(f.z), u3 = f2bfu(f.w);
    uint2 p;
    p.x = (unsigned)u0 | ((unsigned)u1 << 16);
    p.y = (unsigned)u2 | ((unsigned)u3 << 16);
    *(uint2*)(xbf + 4 * i) = p;
}

// WqkvT[n][k], n in [0,1536), k in [0,512): n<1024 -> Wqk[k][n] ; else Wv[k][n-1024]
__global__ __launch_bounds__(256) void cvt_wqkv(const float* __restrict__ Wqk,
                                                const float* __restrict__ Wv,
                                                unsigned short* __restrict__ WT) {
    int id = blockIdx.x * 256 + threadIdx.x;   // 1536*512 total
    int n = id >> 9, k = id & 511;
    float v = (n < 1024) ? Wqk[(size_t)k * 1024 + n] : Wv[(size_t)k * 512 + (n - 1024)];
    WT[id] = f2bfu(v);
}

__global__ __launch_bounds__(256) void cvt_wproj(const float* __restrict__ W,
                                                 unsigned short* __restrict__ WT) {
    int id = blockIdx.x * 256 + threadIdx.x;   // 512*512 total
    int n = id >> 9, k = id & 511;
    WT[id] = f2bfu(W[(size_t)k * 512 + n]);
}

// ---------------- stable counting sort per batch ----------------
__global__ __launch_bounds__(256) void sort_kernel(const int* __restrict__ idx_cluster,
                                                   int* __restrict__ shuf,
                                                   int* __restrict__ restore,
                                                   int* __restrict__ svals,
                                                   int* __restrict__ dbl,
                                                   int* __restrict__ cstart) {
    int b = blockIdx.x, t = threadIdx.x;
    __shared__ int vals[N_];
    __shared__ int seghist[256 * 17];   // stride 17 to spread banks
    __shared__ int cbase[NC_], ctot[NC_];
    __shared__ int shufs[N_];
    const int* src = idx_cluster + (size_t)b * N_;
    for (int j = t; j < N_; j += 256) vals[j] = src[j];
    for (int c = 0; c < NC_; ++c) seghist[t * 17 + c] = 0;
    __syncthreads();
    // count: thread t owns positions t*8 .. t*8+7 (contiguous -> stable)
    for (int i = 0; i < 8; ++i) {
        int c = vals[t * 8 + i];
        seghist[t * 17 + c]++;
    }
    __syncthreads();
    if (t < NC_) {   // exclusive scan over segments for cluster t
        int run = 0;
        for (int s = 0; s < 256; ++s) {
            int x = seghist[s * 17 + t];
            seghist[s * 17 + t] = run;
            run += x;
        }
        ctot[t] = run;
    }
    __syncthreads();
    if (t == 0) {
        int run = 0;
        for (int c = 0; c < NC_; ++c) {
            cbase[c] = run;
            cstart[b * 17 + c] = run;
            run += ctot[c];
        }
        cstart[b * 17 + NC_] = run;   // == N_
    }
    __syncthreads();
    for (int i = 0; i < 8; ++i) {
        int p = t * 8 + i;
        int c = vals[p];
        int pos = cbase[c] + seghist[t * 17 + c];
        seghist[t * 17 + c]++;
        shufs[pos] = p;
    }
    __syncthreads();
    for (int j = t; j < N_; j += 256) {
        int sj = shufs[j];
        shuf[(size_t)b * N_ + j] = sj;
        svals[(size_t)b * N_ + j] = vals[sj];
        restore[(size_t)b * N_ + sj] = j;
        dbl[(size_t)b * N_ + j] = shufs[sj];
    }
}

// ---------------- bf16 MFMA GEMM, A (MxK) row-major, Bt (NxK) row-major ----------------
// MODE 0: qkv  (N=1536) -> split bf16 q/k/v
// MODE 1: attn (per-batch 2048x2048) -> f32 * SCALE
// MODE 2: proj (N=512) -> f32 + bias
template <int MODE>
__global__ __launch_bounds__(256) void gemm_bt(const unsigned short* __restrict__ A,
                                               const unsigned short* __restrict__ Bt,
                                               float* __restrict__ outF,
                                               unsigned short* __restrict__ outQ,
                                               unsigned short* __restrict__ outK,
                                               unsigned short* __restrict__ outV,
                                               const float* __restrict__ bias) {
    constexpr int K = 512;
    int t = threadIdx.x;
    int lane = t & 63, wave = t >> 6;
    int wm = (wave & 1) * 64, wn = (wave >> 1) * 64;
    int m0 = blockIdx.y * 128, n0 = blockIdx.x * 128;
    if (MODE == 1) {
        size_t b = blockIdx.z;
        A += b * (size_t)N_ * 512;
        Bt += b * (size_t)N_ * 512;
        outF += b * (size_t)N_ * N_;
    }
    __shared__ __align__(16) unsigned short As[128 * 72];
    __shared__ __align__(16) unsigned short Bs[128 * 72];
    floatx4 acc[4][4] = {};
    int l15 = lane & 15, q4 = lane >> 4;

    for (int k0 = 0; k0 < K; k0 += 64) {
        __syncthreads();   // previous-iter LDS reads done before overwrite
#pragma unroll
        for (int i = 0; i < 4; ++i) {
            int id = i * 256 + t;
            int row = id >> 3, cs = (id & 7) * 8;
            *(uint4*)(&As[row * 72 + cs]) = *(const uint4*)(A + (size_t)(m0 + row) * 512 + k0 + cs);
            *(uint4*)(&Bs[row * 72 + cs]) = *(const uint4*)(Bt + (size_t)(n0 + row) * 512 + k0 + cs);
        }
        __syncthreads();
#pragma unroll
        for (int kk = 0; kk < 2; ++kk) {
            short8 af[4], bfr[4];
#pragma unroll
            for (int mi = 0; mi < 4; ++mi)
                af[mi] = *(const short8*)(&As[(wm + mi * 16 + l15) * 72 + kk * 32 + q4 * 8]);
#pragma unroll
            for (int ni = 0; ni < 4; ++ni)
                bfr[ni] = *(const short8*)(&Bs[(wn + ni * 16 + l15) * 72 + kk * 32 + q4 * 8]);
#pragma unroll
            for (int mi = 0; mi < 4; ++mi)
#pragma unroll
                for (int ni = 0; ni < 4; ++ni)
                    acc[mi][ni] = __builtin_amdgcn_mfma_f32_16x16x32_bf16(af[mi], bfr[ni], acc[mi][ni], 0, 0, 0);
        }
    }
    // epilogue: D[row=q4*4+r][col=l15] per 16x16 tile
#pragma unroll
    for (int mi = 0; mi < 4; ++mi) {
#pragma unroll
        for (int ni = 0; ni < 4; ++ni) {
#pragma unroll
            for (int r = 0; r < 4; ++r) {
                int row = m0 + wm + mi * 16 + q4 * 4 + r;
                int col = n0 + wn + ni * 16 + l15;
                float v = acc[mi][ni][r];
                if (MODE == 0) {
                    unsigned short u = f2bfu(v);
                    if (col < 512)       outQ[(size_t)row * 512 + col] = u;
                    else if (col < 1024) outK[(size_t)row * 512 + col - 512] = u;
                    else                 outV[(size_t)row * 512 + col - 1024] = u;
                } else if (MODE == 1) {
                    outF[(size_t)row * N_ + col] = v * 0.125f;
                } else {
                    outF[(size_t)row * 512 + col] = v + bias[col];
                }
            }
        }
    }
}

// ---------------- per-(batch,cluster) softmax-collapse reduction ----------------
// e_j = exp(attn[b, dbl[j], j]); O[b,c,d] = sum_j e_j * v[b,shuf[j],d] / sum_j e_j
// stored transposed: Ot[b][d][c]  (d in [0,512), c in [0,16))
__global__ __launch_bounds__(256) void cluster_reduce(const float* __restrict__ attn,
                                                      const int* __restrict__ shuf,
                                                      const int* __restrict__ dbl,
                                                      const int* __restrict__ cstart,
                                                      const unsigned short* __restrict__ vbf,
                                                      float* __restrict__ Ot) {
    int c = blockIdx.x, b = blockIdx.y, t = threadIdx.x;
    int start = cstart[b * 17 + c], end = cstart[b * 17 + c + 1];
    int n = end - start;
    if (n <= 0) return;   // uniform across block; O[b][*][c] never read if cluster empty
    __shared__ float e_lds[N_];
    __shared__ float Sred;
    if (t == 0) Sred = 0.f;
    __syncthreads();
    float ps = 0.f;
    for (int i = t; i < n; i += 256) {
        int j = start + i;
        int dj = dbl[(size_t)b * N_ + j];
        float cv = attn[(size_t)b * N_ * N_ + (size_t)dj * N_ + j];
        float e = expf(cv);
        e_lds[i] = e;
        ps += e;
    }
    atomicAdd(&Sred, ps);
    __syncthreads();
    float t0 = 0.f, t1 = 0.f;
    for (int i = 0; i < n; ++i) {
        float e = e_lds[i];
        int row = shuf[(size_t)b * N_ + start + i];
        const unsigned short* vr = vbf + ((size_t)b * N_ + row) * 512;
        t0 += e * bfu2f(vr[t]);
        t1 += e * bfu2f(vr[t + 256]);
    }
    float inv = 1.f / Sred;
    Ot[((size_t)b * 512 + t) * 16 + c] = t0 * inv;
    Ot[((size_t)b * 512 + t + 256) * 16 + c] = t1 * inv;
}

// ---------------- build out3 (bf16) = transpose-reshape-gather of O ----------------
// out3[b,n,cd] = O[b, s[b,(r&3)*512+cd], r>>2],  r = restore[b,n]
__global__ __launch_bounds__(256) void build_out3(const float* __restrict__ Ot,
                                                  const int* __restrict__ svals,
                                                  const int* __restrict__ restore,
                                                  unsigned int* __restrict__ out3u) {
    int rg = blockIdx.x, b = blockIdx.y, t = threadIdx.x;
    __shared__ float Olds[512 * 16];
    __shared__ int slds[N_];
    for (int i = t; i < 512 * 16; i += 256) Olds[i] = Ot[(size_t)b * 512 * 16 + i];
    for (int i = t; i < N_; i += 256) slds[i] = svals[(size_t)b * N_ + i];
    __syncthreads();
    for (int n = rg * 64; n < rg * 64 + 64; ++n) {
        int r = restore[(size_t)b * N_ + n];
        int rq = r >> 2;
        int bj = (r & 3) * 512;
        int c0 = slds[bj + 2 * t];
        int c1 = slds[bj + 2 * t + 1];
        float v0 = Olds[rq * 16 + c0];
        float v1 = Olds[rq * 16 + c1];
        unsigned p = (unsigned)f2bfu(v0) | ((unsigned)f2bfu(v1) << 16);
        out3u[((size_t)b * N_ + n) * 256 + t] = p;
    }
}

// ---------------- launch ----------------
extern "C" void kernel_launch(void* const* d_in, const int* in_sizes, int n_in,
                              void* d_out, int out_size, void* d_ws, size_t ws_size,
                              hipStream_t stream) {
    const float* x_token = (const float*)d_in[0];
    const int* idx_cluster = (const int*)d_in[2];
    const float* Wqk = (const float*)d_in[4];
    const float* Wv = (const float*)d_in[5];
    const float* Wproj = (const float*)d_in[7];
    const float* bproj = (const float*)d_in[8];

    float* x_out = (float*)d_out;                               // [8][2048][512]
    float* attn = x_out + (size_t)B_ * N_ * C_;                 // [8][2048][2048]

    char* ws = (char*)d_ws;
    size_t off = 0;
    auto alloc = [&](size_t bytes) {
        void* p = ws + off;
        off += (bytes + 255) & ~(size_t)255;
        return p;
    };
    unsigned short* WqkvT = (unsigned short*)alloc(1536 * 512 * 2);
    unsigned short* WprojT = (unsigned short*)alloc(512 * 512 * 2);
    unsigned short* xbf = (unsigned short*)alloc((size_t)B_ * N_ * C_ * 2);   // reused as out3
    unsigned short* qbf = (unsigned short*)alloc((size_t)B_ * N_ * C_ * 2);
    unsigned short* kbf = (unsigned short*)alloc((size_t)B_ * N_ * C_ * 2);
    unsigned short* vbf = (unsigned short*)alloc((size_t)B_ * N_ * C_ * 2);
    int* shuf = (int*)alloc((size_t)B_ * N_ * 4);
    int* restore = (int*)alloc((size_t)B_ * N_ * 4);
    int* svals = (int*)alloc((size_t)B_ * N_ * 4);
    int* dbl = (int*)alloc((size_t)B_ * N_ * 4);
    int* cstart = (int*)alloc(B_ * 17 * 4);
    float* Ot = (float*)alloc((size_t)B_ * 512 * 16 * 4);

    // 1. converts
    cvt_x<<<dim3((B_ * N_ * C_) / (256 * 4)), dim3(256), 0, stream>>>((const float4*)x_token, xbf);
    cvt_wqkv<<<dim3((1536 * 512) / 256), dim3(256), 0, stream>>>(Wqk, Wv, WqkvT);
    cvt_wproj<<<dim3((512 * 512) / 256), dim3(256), 0, stream>>>(Wproj, WprojT);

    // 2. stable sort / index tables
    sort_kernel<<<dim3(B_), dim3(256), 0, stream>>>(idx_cluster, shuf, restore, svals, dbl, cstart);

    // 3. fused qkv GEMM: [16384x512] @ [512x1536]
    gemm_bt<0><<<dim3(1536 / 128, 16384 / 128, 1), dim3(256), 0, stream>>>(
        xbf, WqkvT, nullptr, qbf, kbf, vbf, nullptr);

    // 4. attn_map = q @ k^T * SCALE  (per batch) -> output chunk 1
    gemm_bt<1><<<dim3(N_ / 128, N_ / 128, B_), dim3(256), 0, stream>>>(
        qbf, kbf, attn, nullptr, nullptr, nullptr, nullptr);

    // 5. softmax-collapse per (batch, cluster)
    cluster_reduce<<<dim3(NC_, B_), dim3(256), 0, stream>>>(attn, shuf, dbl, cstart, vbf, Ot);

    // 6. gather into out3 (bf16, aliases xbf)
    build_out3<<<dim3(N_ / 64, B_), dim3(256), 0, stream>>>(Ot, svals, restore, (unsigned int*)xbf);

    // 7. x_out = out3 @ Wproj + bproj -> output chunk 0
    gemm_bt<2><<<dim3(512 / 128, 16384 / 128, 1), dim3(256), 0, stream>>>(
        xbf, WprojT, x_out, nullptr, nullptr, nullptr, bproj);
}

// Round 2
// 346.566 us; speedup vs baseline: 1.0124x; 1.0124x over previous
//
#include <hip/hip_runtime.h>
#include <hip/hip_bf16.h>

// ---------------- helpers ----------------
typedef __attribute__((ext_vector_type(8))) short short8;
typedef __attribute__((ext_vector_type(4))) float floatx4;

__device__ __forceinline__ unsigned short f2bfu(float f) {
    unsigned u = __float_as_uint(f);
    unsigned rounding = 0x7fffu + ((u >> 16) & 1u);
    return (unsigned short)((u + rounding) >> 16);
}
__device__ __forceinline__ float bfu2f(unsigned short u) {
    return __uint_as_float(((unsigned)u) << 16);
}

// async global->LDS, 16B per lane; LDS dest = wave-uniform base + lane*16
__device__ __forceinline__ void async_ld16(const void* g, void* l) {
    __builtin_amdgcn_global_load_lds(
        (const __attribute__((address_space(1))) void*)g,
        (__attribute__((address_space(3))) void*)l, 16, 0, 0);
}

#define B_  8
#define N_  2048
#define C_  512
#define NC_ 16   // clusters

// ---------------- convert kernels ----------------
__global__ __launch_bounds__(256) void cvt_x(const float4* __restrict__ x,
                                             unsigned short* __restrict__ xbf) {
    size_t i = (size_t)blockIdx.x * 256 + threadIdx.x;   // 4 floats per thread
    float4 f = x[i];
    unsigned short u0 = f2bfu(f.x), u1 = f2bfu(f.y), u2 = f2bfu(f.z), u3 = f2bfu(f.w);
    uint2 p;
    p.x = (unsigned)u0 | ((unsigned)u1 << 16);
    p.y = (unsigned)u2 | ((unsigned)u3 << 16);
    *(uint2*)(xbf + 4 * i) = p;
}

// WqkvT[n][k], n in [0,1536), k in [0,512): n<1024 -> Wqk[k][n] ; else Wv[k][n-1024]
__global__ __launch_bounds__(256) void cvt_wqkv(const float* __restrict__ Wqk,
                                                const float* __restrict__ Wv,
                                                unsigned short* __restrict__ WT) {
    int id = blockIdx.x * 256 + threadIdx.x;   // 1536*512 total
    int n = id >> 9, k = id & 511;
    float v = (n < 1024) ? Wqk[(size_t)k * 1024 + n] : Wv[(size_t)k * 512 + (n - 1024)];
    WT[id] = f2bfu(v);
}

__global__ __launch_bounds__(256) void cvt_wproj(const float* __restrict__ W,
                                                 unsigned short* __restrict__ WT) {
    int id = blockIdx.x * 256 + threadIdx.x;   // 512*512 total
    int n = id >> 9, k = id & 511;
    WT[id] = f2bfu(W[(size_t)k * 512 + n]);
}

// ---------------- stable counting sort per batch ----------------
__global__ __launch_bounds__(256) void sort_kernel(const int* __restrict__ idx_cluster,
                                                   int* __restrict__ shuf,
                                                   int* __restrict__ restore,
                                                   int* __restrict__ svals,
                                                   int* __restrict__ dbl,
                                                   int* __restrict__ cstart) {
    int b = blockIdx.x, t = threadIdx.x;
    __shared__ int vals[N_];
    __shared__ int seghist[256 * 17];   // stride 17 to spread banks
    __shared__ int cbase[NC_], ctot[NC_];
    __shared__ int shufs[N_];
    const int* src = idx_cluster + (size_t)b * N_;
    for (int j = t; j < N_; j += 256) vals[j] = src[j];
    for (int c = 0; c < NC_; ++c) seghist[t * 17 + c] = 0;
    __syncthreads();
    // count: thread t owns positions t*8 .. t*8+7 (contiguous -> stable)
    for (int i = 0; i < 8; ++i) {
        int c = vals[t * 8 + i];
        seghist[t * 17 + c]++;
    }
    __syncthreads();
    if (t < NC_) {   // exclusive scan over segments for cluster t
        int run = 0;
        for (int s = 0; s < 256; ++s) {
            int x = seghist[s * 17 + t];
            seghist[s * 17 + t] = run;
            run += x;
        }
        ctot[t] = run;
    }
    __syncthreads();
    if (t == 0) {
        int run = 0;
        for (int c = 0; c < NC_; ++c) {
            cbase[c] = run;
            cstart[b * 17 + c] = run;
            run += ctot[c];
        }
        cstart[b * 17 + NC_] = run;   // == N_
    }
    __syncthreads();
    for (int i = 0; i < 8; ++i) {
        int p = t * 8 + i;
        int c = vals[p];
        int pos = cbase[c] + seghist[t * 17 + c];
        seghist[t * 17 + c]++;
        shufs[pos] = p;
    }
    __syncthreads();
    for (int j = t; j < N_; j += 256) {
        int sj = shufs[j];
        shuf[(size_t)b * N_ + j] = sj;
        svals[(size_t)b * N_ + j] = vals[sj];
        restore[(size_t)b * N_ + sj] = j;
        dbl[(size_t)b * N_ + j] = shufs[sj];
    }
}

// ---------------- bf16 MFMA GEMM, A (MxK) row-major, Bt (NxK) row-major ----------------
// m97 pattern: global_load_lds width=16 staging, unpadded 128x64 LDS tiles,
// source-side XOR swizzle (chunk ^= row&7) to kill ds_read_b128 bank conflicts.
// MODE 0: qkv  (N=1536) -> split bf16 q/k/v
// MODE 1: attn (per-batch 2048x2048) -> f32 * SCALE
// MODE 2: proj (N=512) -> f32 + bias
template <int MODE>
__global__ __launch_bounds__(256) void gemm_bt(const unsigned short* __restrict__ A,
                                               const unsigned short* __restrict__ Bt,
                                               float* __restrict__ outF,
                                               unsigned short* __restrict__ outQ,
                                               unsigned short* __restrict__ outK,
                                               unsigned short* __restrict__ outV,
                                               const float* __restrict__ bias) {
    constexpr int K = 512;
    int t = threadIdx.x;
    int lane = t & 63, wave = t >> 6;
    int wm = (wave & 1) * 64, wn = (wave >> 1) * 64;
    int m0 = blockIdx.y * 128, n0 = blockIdx.x * 128;
    if (MODE == 1) {
        size_t b = blockIdx.z;
        A += b * (size_t)N_ * 512;
        Bt += b * (size_t)N_ * 512;
        outF += b * (size_t)N_ * N_;
    }
    __shared__ __align__(16) unsigned short As[128 * 64];
    __shared__ __align__(16) unsigned short Bs[128 * 64];
    floatx4 acc[4][4] = {};
    int l15 = lane & 15, q4 = lane >> 4;
    // staging: lane covers row (lane>>3) within its 8-row group, chunk (lane&7)
    int srow = lane >> 3, schk = lane & 7;
    int sgc = schk ^ srow;            // source chunk after XOR swizzle (row&7 == srow)
    int xr = l15 & 7;                 // fragment-read XOR (row&7 == l15&7 for all mi/ni)

    for (int k0 = 0; k0 < K; k0 += 64) {
        __syncthreads();   // previous-iter LDS reads done before overwrite
#pragma unroll
        for (int i = 0; i < 4; ++i) {
            int cid = i * 4 + wave;                 // 1KB group id (16 groups of 8 rows)
            int row = cid * 8 + srow;
            async_ld16(A + (size_t)(m0 + row) * 512 + k0 + sgc * 8, (char*)As + cid * 1024);
            async_ld16(Bt + (size_t)(n0 + row) * 512 + k0 + sgc * 8, (char*)Bs + cid * 1024);
        }
        __syncthreads();   // drains vmcnt (async LDS writes visible)
#pragma unroll
        for (int kk = 0; kk < 2; ++kk) {
            int csw = (((kk * 4 + q4) ^ xr) * 8);   // swizzled chunk offset (elements)
            short8 af[4], bfr[4];
#pragma unroll
            for (int mi = 0; mi < 4; ++mi)
                af[mi] = *(const short8*)(&As[(wm + mi * 16 + l15) * 64 + csw]);
#pragma unroll
            for (int ni = 0; ni < 4; ++ni)
                bfr[ni] = *(const short8*)(&Bs[(wn + ni * 16 + l15) * 64 + csw]);
#pragma unroll
            for (int mi = 0; mi < 4; ++mi)
#pragma unroll
                for (int ni = 0; ni < 4; ++ni)
                    acc[mi][ni] = __builtin_amdgcn_mfma_f32_16x16x32_bf16(af[mi], bfr[ni], acc[mi][ni], 0, 0, 0);
        }
    }
    // epilogue: D[row=q4*4+r][col=l15] per 16x16 tile
#pragma unroll
    for (int mi = 0; mi < 4; ++mi) {
#pragma unroll
        for (int ni = 0; ni < 4; ++ni) {
#pragma unroll
            for (int r = 0; r < 4; ++r) {
                int row = m0 + wm + mi * 16 + q4 * 4 + r;
                int col = n0 + wn + ni * 16 + l15;
                float v = acc[mi][ni][r];
                if (MODE == 0) {
                    unsigned short u = f2bfu(v);
                    if (col < 512)       outQ[(size_t)row * 512 + col] = u;
                    else if (col < 1024) outK[(size_t)row * 512 + col - 512] = u;
                    else                 outV[(size_t)row * 512 + col - 1024] = u;
                } else if (MODE == 1) {
                    outF[(size_t)row * N_ + col] = v * 0.125f;
                } else {
                    outF[(size_t)row * 512 + col] = v + bias[col];
                }
            }
        }
    }
}

// ---------------- per-(batch,cluster) softmax-collapse reduction ----------------
// e_j = exp(attn[b, dbl[j], j]); O[b,c,d] = sum_j e_j * v[b,shuf[j],d] / sum_j e_j
// stored transposed: Ot[b][d][c]  (d in [0,512), c in [0,16))
__global__ __launch_bounds__(256) void cluster_reduce(const float* __restrict__ attn,
                                                      const int* __restrict__ shuf,
                                                      const int* __restrict__ dbl,
                                                      const int* __restrict__ cstart,
                                                      const unsigned short* __restrict__ vbf,
                                                      float* __restrict__ Ot) {
    int c = blockIdx.x, b = blockIdx.y, t = threadIdx.x;
    int start = cstart[b * 17 + c], end = cstart[b * 17 + c + 1];
    int n = end - start;
    if (n <= 0) return;   // uniform across block; O[b][*][c] never read if cluster empty
    __shared__ float e_lds[N_];
    __shared__ float Sred;
    if (t == 0) Sred = 0.f;
    __syncthreads();
    float ps = 0.f;
    for (int i = t; i < n; i += 256) {
        int j = start + i;
        int dj = dbl[(size_t)b * N_ + j];
        float cv = attn[(size_t)b * N_ * N_ + (size_t)dj * N_ + j];
        float e = expf(cv);
        e_lds[i] = e;
        ps += e;
    }
    atomicAdd(&Sred, ps);
    __syncthreads();
    float t0 = 0.f, t1 = 0.f;
    for (int i = 0; i < n; ++i) {
        float e = e_lds[i];
        int row = shuf[(size_t)b * N_ + start + i];
        const unsigned short* vr = vbf + ((size_t)b * N_ + row) * 512;
        t0 += e * bfu2f(vr[t]);
        t1 += e * bfu2f(vr[t + 256]);
    }
    float inv = 1.f / Sred;
    Ot[((size_t)b * 512 + t) * 16 + c] = t0 * inv;
    Ot[((size_t)b * 512 + t + 256) * 16 + c] = t1 * inv;
}

// ---------------- build out3 (bf16) = transpose-reshape-gather of O ----------------
// out3[b,n,cd] = O[b, s[b,(r&3)*512+cd], r>>2],  r = restore[b,n]
__global__ __launch_bounds__(256) void build_out3(const float* __restrict__ Ot,
                                                  const int* __restrict__ svals,
                                                  const int* __restrict__ restore,
                                                  unsigned int* __restrict__ out3u) {
    int rg = blockIdx.x, b = blockIdx.y, t = threadIdx.x;
    __shared__ float Olds[512 * 16];
    __shared__ int slds[N_];
    for (int i = t; i < 512 * 16; i += 256) Olds[i] = Ot[(size_t)b * 512 * 16 + i];
    for (int i = t; i < N_; i += 256) slds[i] = svals[(size_t)b * N_ + i];
    __syncthreads();
    for (int n = rg * 64; n < rg * 64 + 64; ++n) {
        int r = restore[(size_t)b * N_ + n];
        int rq = r >> 2;
        int bj = (r & 3) * 512;
        int c0 = slds[bj + 2 * t];
        int c1 = slds[bj + 2 * t + 1];
        float v0 = Olds[rq * 16 + c0];
        float v1 = Olds[rq * 16 + c1];
        unsigned p = (unsigned)f2bfu(v0) | ((unsigned)f2bfu(v1) << 16);
        out3u[((size_t)b * N_ + n) * 256 + t] = p;
    }
}

// ---------------- launch ----------------
extern "C" void kernel_launch(void* const* d_in, const int* in_sizes, int n_in,
                              void* d_out, int out_size, void* d_ws, size_t ws_size,
                              hipStream_t stream) {
    const float* x_token = (const float*)d_in[0];
    const int* idx_cluster = (const int*)d_in[2];
    const float* Wqk = (const float*)d_in[4];
    const float* Wv = (const float*)d_in[5];
    const float* Wproj = (const float*)d_in[7];
    const float* bproj = (const float*)d_in[8];

    float* x_out = (float*)d_out;                               // [8][2048][512]
    float* attn = x_out + (size_t)B_ * N_ * C_;                 // [8][2048][2048]

    char* ws = (char*)d_ws;
    size_t off = 0;
    auto alloc = [&](size_t bytes) {
        void* p = ws + off;
        off += (bytes + 255) & ~(size_t)255;
        return p;
    };
    unsigned short* WqkvT = (unsigned short*)alloc(1536 * 512 * 2);
    unsigned short* WprojT = (unsigned short*)alloc(512 * 512 * 2);
    unsigned short* xbf = (unsigned short*)alloc((size_t)B_ * N_ * C_ * 2);   // reused as out3
    unsigned short* qbf = (unsigned short*)alloc((size_t)B_ * N_ * C_ * 2);
    unsigned short* kbf = (unsigned short*)alloc((size_t)B_ * N_ * C_ * 2);
    unsigned short* vbf = (unsigned short*)alloc((size_t)B_ * N_ * C_ * 2);
    int* shuf = (int*)alloc((size_t)B_ * N_ * 4);
    int* restore = (int*)alloc((size_t)B_ * N_ * 4);
    int* svals = (int*)alloc((size_t)B_ * N_ * 4);
    int* dbl = (int*)alloc((size_t)B_ * N_ * 4);
    int* cstart = (int*)alloc(B_ * 17 * 4);
    float* Ot = (float*)alloc((size_t)B_ * 512 * 16 * 4);

    // 1. converts
    cvt_x<<<dim3((B_ * N_ * C_) / (256 * 4)), dim3(256), 0, stream>>>((const float4*)x_token, xbf);
    cvt_wqkv<<<dim3((1536 * 512) / 256), dim3(256), 0, stream>>>(Wqk, Wv, WqkvT);
    cvt_wproj<<<dim3((512 * 512) / 256), dim3(256), 0, stream>>>(Wproj, WprojT);

    // 2. stable sort / index tables
    sort_kernel<<<dim3(B_), dim3(256), 0, stream>>>(idx_cluster, shuf, restore, svals, dbl, cstart);

    // 3. fused qkv GEMM: [16384x512] @ [512x1536]
    gemm_bt<0><<<dim3(1536 / 128, 16384 / 128, 1), dim3(256), 0, stream>>>(
        xbf, WqkvT, nullptr, qbf, kbf, vbf, nullptr);

    // 4. attn_map = q @ k^T * SCALE  (per batch) -> output chunk 1
    gemm_bt<1><<<dim3(N_ / 128, N_ / 128, B_), dim3(256), 0, stream>>>(
        qbf, kbf, attn, nullptr, nullptr, nullptr, nullptr);

    // 5. softmax-collapse per (batch, cluster)
    cluster_reduce<<<dim3(NC_, B_), dim3(256), 0, stream>>>(attn, shuf, dbl, cstart, vbf, Ot);

    // 6. gather into out3 (bf16, aliases xbf)
    build_out3<<<dim3(N_ / 64, B_), dim3(256), 0, stream>>>(Ot, svals, restore, (unsigned int*)xbf);

    // 7. x_out = out3 @ Wproj + bproj -> output chunk 0
    gemm_bt<2><<<dim3(512 / 128, 16384 / 128, 1), dim3(256), 0, stream>>>(
        xbf, WprojT, x_out, nullptr, nullptr, nullptr, bproj);
}